// Round 8
// baseline (164.703 us; speedup 1.0000x reference)
//
#include <hip/hip_runtime.h>
#include <stdint.h>

typedef unsigned short u16;
typedef __bf16 bf16x8 __attribute__((ext_vector_type(8)));
typedef unsigned short u16x8 __attribute__((ext_vector_type(8)));
typedef unsigned short u16x4 __attribute__((ext_vector_type(4)));
typedef float f32x4 __attribute__((ext_vector_type(4)));

#define MFMA16(a, b, c) __builtin_amdgcn_mfma_f32_16x16x32_bf16((a), (b), (c), 0, 0, 0)

__device__ __forceinline__ u16 f2b(float f) {
    union { unsigned int i; float f; } v; v.f = f;
    unsigned int r = (v.i + 0x7FFFu + ((v.i >> 16) & 1u)) >> 16;
    return (u16)r;
}

constexpr int N = 4096;
constexpr int Cc = 128;
constexpr int Fc = 128;
constexpr int BATCH = 4;

constexpr int XS_STRIDE = 136;
constexpr int WT_STRIDE = 136;
constexpr int KS_STRIDE = 136;   // K tile [key128][c]
constexpr int VTS_STRIDE = 136;  // V tile [ch][key128]

// ---------------------------------------------------------------------------
// W pre-transpose: Wt[which][f][c] (bf16). grid 3 x 256.
// ---------------------------------------------------------------------------
__global__ __launch_bounds__(256) void wtrans_kernel(
    const float* __restrict__ Wq, const float* __restrict__ Wk,
    const float* __restrict__ Wv, u16* __restrict__ WtG)
{
    __shared__ __align__(16) u16 Wl[128 * 132];  // [c][f]
    const int tid = threadIdx.x;
    const int which = blockIdx.x;
    const float* W = which == 0 ? Wq : (which == 1 ? Wk : Wv);
#pragma unroll
    for (int it = 0; it < 16; ++it) {
        int idx4 = tid + it * 256; int e0 = idx4 * 4;
        int c = e0 >> 7, f = e0 & 127;
        float4 wv = *(const float4*)(W + e0);
        u16x4 h; h[0] = f2b(wv.x); h[1] = f2b(wv.y); h[2] = f2b(wv.z); h[3] = f2b(wv.w);
        *(u16x4*)&Wl[c * 132 + f] = h;
    }
    __syncthreads();
    u16* out = WtG + which * 16384;
#pragma unroll
    for (int it = 0; it < 8; ++it) {
        int idx8 = tid + it * 256; int e0 = idx8 * 8;
        int f = e0 >> 7, c = e0 & 127;
        u16x8 h;
#pragma unroll
        for (int j = 0; j < 8; ++j) h[j] = Wl[(c + j) * 132 + f];
        *(u16x8*)(out + e0) = h;
    }
}

// ---------------------------------------------------------------------------
// Projection (fp32 X, bf16 Wt -> bf16 workspace). grid (64,3,4) x 256.
// ---------------------------------------------------------------------------
__global__ __launch_bounds__(256) void proj_kernel(
    const float* __restrict__ q_in, const float* __restrict__ kv_in,
    const u16* __restrict__ WtG,
    const float* __restrict__ bq, const float* __restrict__ bk,
    const float* __restrict__ bv,
    u16* __restrict__ Qw, u16* __restrict__ Kw, u16* __restrict__ Vtw)
{
    __shared__ __align__(16) u16 Xs[64 * XS_STRIDE];   // [m][c] bf16
    __shared__ __align__(16) u16 Wt[128 * WT_STRIDE];  // [f][c] bf16

    const int tid = threadIdx.x;
    const int which = blockIdx.y;
    const int b = blockIdx.z;
    const int m0 = blockIdx.x * 64;

    const float* X = (which == 0 ? q_in : kv_in) + ((size_t)b * N + m0) * Cc;
    const u16* Wsrc = WtG + which * 16384;
    const float* bias = which == 0 ? bq : (which == 1 ? bk : bv);

#pragma unroll
    for (int it = 0; it < 8; ++it) {
        int idx4 = tid + it * 256; int e0 = idx4 * 4;
        int r = e0 >> 7, c = e0 & 127;
        float4 xv = *(const float4*)(X + e0);
        u16x4 h; h[0] = f2b(xv.x); h[1] = f2b(xv.y); h[2] = f2b(xv.z); h[3] = f2b(xv.w);
        *(u16x4*)&Xs[r * XS_STRIDE + c] = h;
    }
#pragma unroll
    for (int it = 0; it < 8; ++it) {
        int idx8 = tid + it * 256; int e0 = idx8 * 8;
        int f = e0 >> 7, c = e0 & 127;
        *(u16x8*)&Wt[f * WT_STRIDE + c] = *(const u16x8*)(Wsrc + e0);
    }
    __syncthreads();

    const int lane = tid & 63;
    const int w = tid >> 6;
    const int n16 = lane & 15;
    const int quad = lane >> 4;

    if (which < 2) {
        bf16x8 ax[4];
#pragma unroll
        for (int kk = 0; kk < 4; ++kk)
            ax[kk] = *(const bf16x8*)&Xs[(w * 16 + n16) * XS_STRIDE + kk * 32 + quad * 8];
        const float scale = (which == 0) ? 0.08838834764831845f : 1.0f;
        u16* Out = (which == 0) ? Qw : Kw;
#pragma unroll
        for (int ft = 0; ft < 8; ++ft) {
            f32x4 acc = {0.f, 0.f, 0.f, 0.f};
#pragma unroll
            for (int kk = 0; kk < 4; ++kk) {
                bf16x8 bw = *(const bf16x8*)&Wt[(ft * 16 + n16) * WT_STRIDE + kk * 32 + quad * 8];
                acc = MFMA16(ax[kk], bw, acc);
            }
            float bias_f = bias[ft * 16 + n16];
#pragma unroll
            for (int r = 0; r < 4; ++r) {
                int row = m0 + w * 16 + quad * 4 + r;
                Out[((size_t)b * N + row) * Fc + ft * 16 + n16] = f2b((acc[r] + bias_f) * scale);
            }
        }
    } else {
#pragma unroll
        for (int ft2 = 0; ft2 < 2; ++ft2) {
            int ftg = w * 2 + ft2;
            bf16x8 aw[4];
#pragma unroll
            for (int kk = 0; kk < 4; ++kk)
                aw[kk] = *(const bf16x8*)&Wt[(ftg * 16 + n16) * WT_STRIDE + kk * 32 + quad * 8];
            float bias4[4];
#pragma unroll
            for (int r = 0; r < 4; ++r) bias4[r] = bias[ftg * 16 + quad * 4 + r];
#pragma unroll
            for (int nt = 0; nt < 4; ++nt) {
                f32x4 acc = {0.f, 0.f, 0.f, 0.f};
#pragma unroll
                for (int kk = 0; kk < 4; ++kk) {
                    bf16x8 bx = *(const bf16x8*)&Xs[(nt * 16 + n16) * XS_STRIDE + kk * 32 + quad * 8];
                    acc = MFMA16(aw[kk], bx, acc);
                }
#pragma unroll
                for (int r = 0; r < 4; ++r) {
                    int fg = ftg * 16 + quad * 4 + r;
                    int rowg = m0 + nt * 16 + n16;
                    Vtw[((size_t)b * Fc + fg) * N + rowg] = f2b(acc[r] + bias4[r]);
                }
            }
        }
    }
}

// ---------------------------------------------------------------------------
// Flash attention (statically-scaled softmax exp(s), deferred l).
// grid (128 q-tiles of 32 rows, 4 batches) = 512 blocks, 512 threads = 8 waves
// = 2 qg (16 q-rows) x 4 kg (32 keys of a 128-key tile). Each block iterates
// ALL 4096 keys (32 tiles); 4-way kg merge in-block via LDS; writes d_out
// directly (no partial buffers -> workspace identical to the passing round-5
// layout, 12.7 MB). LDS 69.6 KB -> 2 blocks/CU; __launch_bounds__(512,4)
// targets VGPR<=128 for 16 waves/CU.
// P C-layout -> A-layout via packed shfl (e[ks0],e[ks1] as bf16 pair; target
// selects half by its own quad>>1 AFTER the shuffle).
// ---------------------------------------------------------------------------
__global__ __launch_bounds__(512, 4) void attn_kernel(
    const u16* __restrict__ Qw, const u16* __restrict__ Kw,
    const u16* __restrict__ Vtw, float* __restrict__ out)
{
    __shared__ __align__(16) char smem[(128 * KS_STRIDE + 128 * VTS_STRIDE) * 2]; // 69632 B
    u16* Ks  = (u16*)smem;               // [128 key][KS_STRIDE]
    u16* Vts = Ks + 128 * KS_STRIDE;     // [128 ch][VTS_STRIDE]
    float* Om = (float*)smem;            // merge phase: [96 rows][132]
    float* Lm = Om + 96 * 132;           // [96]

    const int tid = threadIdx.x;
    const int b = blockIdx.y;
    const int q0 = blockIdx.x * 32;
    const int lane = tid & 63;
    const int w = tid >> 6;      // 0..7
    const int kg = w & 3;        // key quarter (32 keys of the 128-key tile)
    const int qg = w >> 2;       // q group (16 of the block's 32 rows)
    const int n16 = lane & 15;
    const int quad = lane >> 4;

    // Q B-fragment (q = q0 + qg*16 + n16), held for the whole loop
    bf16x8 aq[4];
    {
        const u16* qrow = Qw + ((size_t)b * N + q0 + qg * 16 + n16) * Cc;
#pragma unroll
        for (int kk = 0; kk < 4; ++kk)
            aq[kk] = *(const bf16x8*)(qrow + kk * 32 + quad * 8);
    }

    const u16* Kbase = Kw + (size_t)b * N * Cc;
    const u16* Vbase = Vtw + (size_t)b * Fc * N;

    // prologue: prefetch tile 0 (K: 128x128 row-major; V: 128ch x 128key)
    u16x8 kreg[4], vreg[4];
#pragma unroll
    for (int it = 0; it < 4; ++it) {
        int idx8 = tid + it * 512; int e0 = idx8 * 8;
        kreg[it] = *(const u16x8*)(Kbase + (size_t)(e0 >> 7) * Cc + (e0 & 127));
        vreg[it] = *(const u16x8*)(Vbase + (size_t)(idx8 >> 4) * N + (idx8 & 15) * 8);
    }

    f32x4 o[8];
#pragma unroll
    for (int ct = 0; ct < 8; ++ct) o[ct] = (f32x4){0.f, 0.f, 0.f, 0.f};
    float lloc = 0.f;

    for (int t = 0; t < N / 128; ++t) {
        // commit prefetched tile to LDS
#pragma unroll
        for (int it = 0; it < 4; ++it) {
            int idx8 = tid + it * 512; int e0 = idx8 * 8;
            *(u16x8*)&Ks[(e0 >> 7) * KS_STRIDE + (e0 & 127)] = kreg[it];
            *(u16x8*)&Vts[(idx8 >> 4) * VTS_STRIDE + (idx8 & 15) * 8] = vreg[it];
        }
        __syncthreads();

        // S^T = K Q^T over this wave's 32 keys: st[ks][r] at lane (n16,quad)
        // = P(q = qg*16+n16, key_local = ks*16 + quad*4 + r) of key window kg*32.
        f32x4 st[2];
#pragma unroll
        for (int ks = 0; ks < 2; ++ks) {
            f32x4 acc = {0.f, 0.f, 0.f, 0.f};
#pragma unroll
            for (int kk = 0; kk < 4; ++kk) {
                bf16x8 ak = *(const bf16x8*)&Ks[(kg * 32 + ks * 16 + n16) * KS_STRIDE + kk * 32 + quad * 8];
                acc = MFMA16(ak, aq[kk], acc);
            }
            st[ks] = acc;
        }

        // prefetch next tile (between S and PV: keeps kreg/vreg lifetime off
        // the ak transient, and still ~1 compute-phase of latency lead)
        if (t + 1 < N / 128) {
            int k0n = (t + 1) * 128;
#pragma unroll
            for (int it = 0; it < 4; ++it) {
                int idx8 = tid + it * 512; int e0 = idx8 * 8;
                kreg[it] = *(const u16x8*)(Kbase + (size_t)(k0n + (e0 >> 7)) * Cc + (e0 & 127));
                vreg[it] = *(const u16x8*)(Vbase + (size_t)(idx8 >> 4) * N + k0n + (idx8 & 15) * 8);
            }
        }

        // exp + l partial, then C->A transform via packed shfl.
        // Target lane (n16,quad) elem j needs key_local = quad*8+j:
        //   src lane = n16 + 32*(quad&1) + 16*(j>>2), reg r = j&3,
        //   half = quad>>1 selected in the TARGET lane after the shuffle.
        bf16x8 pa;
        {
            unsigned int packed[4];
#pragma unroll
            for (int r = 0; r < 4; ++r) {
                float e0 = __expf(st[0][r]);
                float e1 = __expf(st[1][r]);
                lloc += e0 + e1;
                packed[r] = (unsigned int)f2b(e0) | ((unsigned int)f2b(e1) << 16);
            }
            const int sbase = n16 + ((quad & 1) << 5);
            union { bf16x8 v; u16x8 h; } pk;
#pragma unroll
            for (int j = 0; j < 8; ++j) {
                unsigned int pv = (unsigned int)__shfl((int)packed[j & 3], sbase + ((j >> 2) << 4));
                pk.h[j] = (quad < 2) ? (u16)(pv & 0xFFFFu) : (u16)(pv >> 16);
            }
            pa = pk.v;
        }

        // O += P V  (A=P[q16][key32], B=Vts[ch][key32]): D[q][ch]
#pragma unroll
        for (int ct = 0; ct < 8; ++ct) {
            bf16x8 bv_ = *(const bf16x8*)&Vts[(ct * 16 + n16) * VTS_STRIDE + kg * 32 + quad * 8];
            o[ct] = MFMA16(pa, bv_, o[ct]);
        }
        __syncthreads();
    }

    // l: sum the 4 quad-copies of each q-column (all lanes get the value)
    float lv = lloc;
    lv += __shfl_xor(lv, 16);
    lv += __shfl_xor(lv, 32);

    // 4-way kg merge through LDS (aliases tile buffers; last loop barrier has
    // already separated the final reads)
    if (kg != 0) {
        int rbase = (kg - 1) * 32 + qg * 16;
#pragma unroll
        for (int ct = 0; ct < 8; ++ct)
#pragma unroll
            for (int r = 0; r < 4; ++r)
                Om[(rbase + quad * 4 + r) * 132 + ct * 16 + n16] = o[ct][r];
        if (quad == 0) Lm[rbase + n16] = lv;
    }
    __syncthreads();
    if (kg == 0) {
        float lsum[4];
#pragma unroll
        for (int r = 0; r < 4; ++r) {
            float s = __shfl(lv, quad * 4 + r);   // lane holds l for q-col n16=quad*4+r
#pragma unroll
            for (int j = 0; j < 3; ++j)
                s += Lm[j * 32 + qg * 16 + quad * 4 + r];
            lsum[r] = s;
        }
#pragma unroll
        for (int ct = 0; ct < 8; ++ct) {
#pragma unroll
            for (int r = 0; r < 4; ++r) {
                float ov = o[ct][r];
#pragma unroll
                for (int j = 0; j < 3; ++j)
                    ov += Om[(j * 32 + qg * 16 + quad * 4 + r) * 132 + ct * 16 + n16];
                int q = q0 + qg * 16 + quad * 4 + r;
                out[((size_t)b * N + q) * Fc + ct * 16 + n16] = ov / lsum[r];
            }
        }
    }
}

extern "C" void kernel_launch(void* const* d_in, const int* in_sizes, int n_in,
                              void* d_out, int out_size, void* d_ws, size_t ws_size,
                              hipStream_t stream) {
    (void)in_sizes; (void)n_in; (void)out_size; (void)ws_size;
    const float* q_in  = (const float*)d_in[0];
    const float* kv_in = (const float*)d_in[1];
    const float* Wq = (const float*)d_in[2];
    const float* bq = (const float*)d_in[3];
    const float* Wk = (const float*)d_in[4];
    const float* bk = (const float*)d_in[5];
    const float* Wv = (const float*)d_in[6];
    const float* bv = (const float*)d_in[7];

    const size_t qkv = (size_t)BATCH * N * Fc;   // 2,097,152 elements
    u16* Qw  = (u16*)d_ws;              // bf16 [b][m][f], pre-scaled
    u16* Kw  = Qw + qkv;                // bf16 [b][m][f]
    u16* Vtw = Kw + qkv;                // bf16 [b][f][m]
    u16* WtG = Vtw + qkv;               // bf16 [3][f][c]  (total ws 12.68 MB)

    wtrans_kernel<<<dim3(3), dim3(256), 0, stream>>>(Wq, Wk, Wv, WtG);
    proj_kernel<<<dim3(64, 3, BATCH), dim3(256), 0, stream>>>(
        q_in, kv_in, WtG, bq, bk, bv, Qw, Kw, Vtw);
    attn_kernel<<<dim3(128, BATCH), dim3(512), 0, stream>>>(
        Qw, Kw, Vtw, (float*)d_out);
}

// Round 9
// 147.628 us; speedup vs baseline: 1.1157x; 1.1157x over previous
//
#include <hip/hip_runtime.h>
#include <stdint.h>

typedef unsigned short u16;
typedef __bf16 bf16x8 __attribute__((ext_vector_type(8)));
typedef unsigned short u16x8 __attribute__((ext_vector_type(8)));
typedef unsigned short u16x4 __attribute__((ext_vector_type(4)));
typedef float f32x4 __attribute__((ext_vector_type(4)));

#define MFMA16(a, b, c) __builtin_amdgcn_mfma_f32_16x16x32_bf16((a), (b), (c), 0, 0, 0)

__device__ __forceinline__ u16 f2b(float f) {
    union { unsigned int i; float f; } v; v.f = f;
    unsigned int r = (v.i + 0x7FFFu + ((v.i >> 16) & 1u)) >> 16;
    return (u16)r;
}

constexpr int N = 4096;
constexpr int Cc = 128;
constexpr int Fc = 128;
constexpr int BATCH = 4;

constexpr int XS_STRIDE = 136;
constexpr int WT_STRIDE = 136;
constexpr int KS_STRIDE = 136;   // K tile [key128][c]
constexpr int VTS_STRIDE = 136;  // V tile [ch][key128]
constexpr int PS_STRIDE = 72;    // per-wave P [16 q][64 key + pad]

// ---------------------------------------------------------------------------
// W pre-transpose: Wt[which][f][c] (bf16). grid 3 x 256.
// ---------------------------------------------------------------------------
__global__ __launch_bounds__(256) void wtrans_kernel(
    const float* __restrict__ Wq, const float* __restrict__ Wk,
    const float* __restrict__ Wv, u16* __restrict__ WtG)
{
    __shared__ __align__(16) u16 Wl[128 * 132];  // [c][f]
    const int tid = threadIdx.x;
    const int which = blockIdx.x;
    const float* W = which == 0 ? Wq : (which == 1 ? Wk : Wv);
#pragma unroll
    for (int it = 0; it < 16; ++it) {
        int idx4 = tid + it * 256; int e0 = idx4 * 4;
        int c = e0 >> 7, f = e0 & 127;
        float4 wv = *(const float4*)(W + e0);
        u16x4 h; h[0] = f2b(wv.x); h[1] = f2b(wv.y); h[2] = f2b(wv.z); h[3] = f2b(wv.w);
        *(u16x4*)&Wl[c * 132 + f] = h;
    }
    __syncthreads();
    u16* out = WtG + which * 16384;
#pragma unroll
    for (int it = 0; it < 8; ++it) {
        int idx8 = tid + it * 256; int e0 = idx8 * 8;
        int f = e0 >> 7, c = e0 & 127;
        u16x8 h;
#pragma unroll
        for (int j = 0; j < 8; ++j) h[j] = Wl[(c + j) * 132 + f];
        *(u16x8*)(out + e0) = h;
    }
}

// ---------------------------------------------------------------------------
// Projection (fp32 X, bf16 Wt -> bf16 workspace). grid (64,3,4) x 256.
// ---------------------------------------------------------------------------
__global__ __launch_bounds__(256) void proj_kernel(
    const float* __restrict__ q_in, const float* __restrict__ kv_in,
    const u16* __restrict__ WtG,
    const float* __restrict__ bq, const float* __restrict__ bk,
    const float* __restrict__ bv,
    u16* __restrict__ Qw, u16* __restrict__ Kw, u16* __restrict__ Vtw)
{
    __shared__ __align__(16) u16 Xs[64 * XS_STRIDE];   // [m][c] bf16
    __shared__ __align__(16) u16 Wt[128 * WT_STRIDE];  // [f][c] bf16

    const int tid = threadIdx.x;
    const int which = blockIdx.y;
    const int b = blockIdx.z;
    const int m0 = blockIdx.x * 64;

    const float* X = (which == 0 ? q_in : kv_in) + ((size_t)b * N + m0) * Cc;
    const u16* Wsrc = WtG + which * 16384;
    const float* bias = which == 0 ? bq : (which == 1 ? bk : bv);

#pragma unroll
    for (int it = 0; it < 8; ++it) {
        int idx4 = tid + it * 256; int e0 = idx4 * 4;
        int r = e0 >> 7, c = e0 & 127;
        float4 xv = *(const float4*)(X + e0);
        u16x4 h; h[0] = f2b(xv.x); h[1] = f2b(xv.y); h[2] = f2b(xv.z); h[3] = f2b(xv.w);
        *(u16x4*)&Xs[r * XS_STRIDE + c] = h;
    }
#pragma unroll
    for (int it = 0; it < 8; ++it) {
        int idx8 = tid + it * 256; int e0 = idx8 * 8;
        int f = e0 >> 7, c = e0 & 127;
        *(u16x8*)&Wt[f * WT_STRIDE + c] = *(const u16x8*)(Wsrc + e0);
    }
    __syncthreads();

    const int lane = tid & 63;
    const int w = tid >> 6;
    const int n16 = lane & 15;
    const int quad = lane >> 4;

    if (which < 2) {
        bf16x8 ax[4];
#pragma unroll
        for (int kk = 0; kk < 4; ++kk)
            ax[kk] = *(const bf16x8*)&Xs[(w * 16 + n16) * XS_STRIDE + kk * 32 + quad * 8];
        const float scale = (which == 0) ? 0.08838834764831845f : 1.0f;
        u16* Out = (which == 0) ? Qw : Kw;
#pragma unroll
        for (int ft = 0; ft < 8; ++ft) {
            f32x4 acc = {0.f, 0.f, 0.f, 0.f};
#pragma unroll
            for (int kk = 0; kk < 4; ++kk) {
                bf16x8 bw = *(const bf16x8*)&Wt[(ft * 16 + n16) * WT_STRIDE + kk * 32 + quad * 8];
                acc = MFMA16(ax[kk], bw, acc);
            }
            float bias_f = bias[ft * 16 + n16];
#pragma unroll
            for (int r = 0; r < 4; ++r) {
                int row = m0 + w * 16 + quad * 4 + r;
                Out[((size_t)b * N + row) * Fc + ft * 16 + n16] = f2b((acc[r] + bias_f) * scale);
            }
        }
    } else {
#pragma unroll
        for (int ft2 = 0; ft2 < 2; ++ft2) {
            int ftg = w * 2 + ft2;
            bf16x8 aw[4];
#pragma unroll
            for (int kk = 0; kk < 4; ++kk)
                aw[kk] = *(const bf16x8*)&Wt[(ftg * 16 + n16) * WT_STRIDE + kk * 32 + quad * 8];
            float bias4[4];
#pragma unroll
            for (int r = 0; r < 4; ++r) bias4[r] = bias[ftg * 16 + quad * 4 + r];
#pragma unroll
            for (int nt = 0; nt < 4; ++nt) {
                f32x4 acc = {0.f, 0.f, 0.f, 0.f};
#pragma unroll
                for (int kk = 0; kk < 4; ++kk) {
                    bf16x8 bx = *(const bf16x8*)&Xs[(nt * 16 + n16) * XS_STRIDE + kk * 32 + quad * 8];
                    acc = MFMA16(aw[kk], bx, acc);
                }
#pragma unroll
                for (int r = 0; r < 4; ++r) {
                    int fg = ftg * 16 + quad * 4 + r;
                    int rowg = m0 + nt * 16 + n16;
                    Vtw[((size_t)b * Fc + fg) * N + rowg] = f2b(acc[r] + bias4[r]);
                }
            }
        }
    }
}

// ---------------------------------------------------------------------------
// Flash attention (statically-scaled softmax exp(s), deferred l).
// Round-4 champion compute shape: 512 threads = 8 waves = 4 wq (16 q-rows) x
// 2 grp (64-key halves); 64 rows/block; 128-key tiles; P via wave-private LDS.
// NEW: double-buffered K/V LDS -> ONE barrier per tile (no read-protection
// barrier, no vmcnt drain at the barrier: the commit already drained it).
// Prefetch issued right after the barrier -> a full compute phase to land.
// grid (64 q-tiles, 4 batches), 512 threads, LDS 157.7 KB (1 block/CU).
// ---------------------------------------------------------------------------
__global__ __launch_bounds__(512, 2) void attn_kernel(
    const u16* __restrict__ Qw, const u16* __restrict__ Kw,
    const u16* __restrict__ Vtw, float* __restrict__ out)
{
    // [Kbuf0 | Kbuf1 | Vbuf0 | Vbuf1 | P]  (u16 elements)
    __shared__ __align__(16) u16 smem[2 * 128 * KS_STRIDE + 2 * 128 * VTS_STRIDE + 8 * 16 * PS_STRIDE];
    u16* Kbuf = smem;                          // 2 x 17408
    u16* Vbuf = smem + 2 * 128 * KS_STRIDE;    // 2 x 17408
    u16* Ps   = Vbuf + 2 * 128 * VTS_STRIDE;   // 8 x 16 x 72

    const int tid = threadIdx.x;
    const int b = blockIdx.y;
    const int q0 = blockIdx.x * 64;
    const int lane = tid & 63;
    const int w = tid >> 6;      // 0..7
    const int wq = w & 3;        // q-row group (16 rows)
    const int grp = w >> 2;      // 64-key half of the 128-key tile
    const int n16 = lane & 15;
    const int quad = lane >> 4;

    // Q B-fragments (q = q0 + wq*16 + n16), held for the whole loop
    bf16x8 aq[4];
    {
        const u16* qrow = Qw + ((size_t)b * N + q0 + wq * 16 + n16) * Cc;
#pragma unroll
        for (int kk = 0; kk < 4; ++kk)
            aq[kk] = *(const bf16x8*)(qrow + kk * 32 + quad * 8);
    }

    // staging maps: 512 threads stage 128x128 K and 128x128 Vt per tile
    int rr[4], cc[4];
#pragma unroll
    for (int it = 0; it < 4; ++it) {
        int idx8 = tid + it * 512; int e0 = idx8 * 8;
        rr[it] = e0 >> 7; cc[it] = e0 & 127;
    }
    const u16* Kbase = Kw + (size_t)b * N * Cc;
    const u16* Vbase = Vtw + (size_t)b * Fc * N;

    // prologue: prefetch tile 0
    u16x8 kreg[4], vreg[4];
#pragma unroll
    for (int it = 0; it < 4; ++it) {
        kreg[it] = *(const u16x8*)(Kbase + (size_t)rr[it] * Cc + cc[it]);
        vreg[it] = *(const u16x8*)(Vbase + (size_t)rr[it] * N + cc[it]);
    }

    f32x4 o[8];
#pragma unroll
    for (int ct = 0; ct < 8; ++ct) o[ct] = (f32x4){0.f, 0.f, 0.f, 0.f};
    float lloc = 0.f;

    u16* Psw = Ps + w * 16 * PS_STRIDE;

    for (int t = 0; t < N / 128; ++t) {
        u16* Ks  = Kbuf + (t & 1) * 128 * KS_STRIDE;
        u16* Vts = Vbuf + (t & 1) * 128 * VTS_STRIDE;

        // commit prefetched tile into this tile's buffer (vmcnt drains here)
#pragma unroll
        for (int it = 0; it < 4; ++it) {
            *(u16x8*)&Ks[rr[it] * KS_STRIDE + cc[it]] = kreg[it];
            *(u16x8*)&Vts[rr[it] * VTS_STRIDE + cc[it]] = vreg[it];
        }
        __syncthreads();   // single barrier per tile (other buffer untouched)

        // prefetch next tile — a full compute phase before its commit
        if (t + 1 < N / 128) {
            int k0n = (t + 1) * 128;
#pragma unroll
            for (int it = 0; it < 4; ++it) {
                kreg[it] = *(const u16x8*)(Kbase + (size_t)(k0n + rr[it]) * Cc + cc[it]);
                vreg[it] = *(const u16x8*)(Vbase + (size_t)rr[it] * N + k0n + cc[it]);
            }
        }

        // S^T = K Q^T over this wave's 64-key half: st[kt][r] at lane(n16,quad)
        // = P(q = n16, key = grp*64 + kt*16 + quad*4 + r)
        f32x4 st[4];
#pragma unroll
        for (int kt = 0; kt < 4; ++kt) {
            f32x4 acc = {0.f, 0.f, 0.f, 0.f};
#pragma unroll
            for (int kk = 0; kk < 4; ++kk) {
                bf16x8 ak = *(const bf16x8*)&Ks[(grp * 64 + kt * 16 + n16) * KS_STRIDE + kk * 32 + quad * 8];
                acc = MFMA16(ak, aq[kk], acc);
            }
            st[kt] = acc;
        }

        // p = exp(s); per-lane l partial; b64 P stores (4 consecutive keys)
#pragma unroll
        for (int kt = 0; kt < 4; ++kt) {
            float e0 = __expf(st[kt][0]), e1 = __expf(st[kt][1]);
            float e2 = __expf(st[kt][2]), e3 = __expf(st[kt][3]);
            lloc += (e0 + e1) + (e2 + e3);
            u16x4 pk; pk[0] = f2b(e0); pk[1] = f2b(e1); pk[2] = f2b(e2); pk[3] = f2b(e3);
            *(u16x4*)&Psw[n16 * PS_STRIDE + kt * 16 + quad * 4] = pk;
        }

        // O += P V  (A = P[q][key], B = Vts[ch][key]); wave-private P buffer
        bf16x8 pa[2];
#pragma unroll
        for (int kch = 0; kch < 2; ++kch)
            pa[kch] = *(const bf16x8*)&Psw[n16 * PS_STRIDE + kch * 32 + quad * 8];
#pragma unroll
        for (int ct = 0; ct < 8; ++ct) {
#pragma unroll
            for (int kch = 0; kch < 2; ++kch) {
                bf16x8 bv_ = *(const bf16x8*)&Vts[(ct * 16 + n16) * VTS_STRIDE + grp * 64 + kch * 32 + quad * 8];
                o[ct] = MFMA16(pa[kch], bv_, o[ct]);
            }
        }
        // no trailing barrier: next tile commits into the other buffer
    }
    __syncthreads();   // protect merge-phase aliasing of the tile buffers

    // l: sum the 4 quad-copies of each q-column (all lanes get the value)
    float lv = lloc;
    lv += __shfl_xor(lv, 16);
    lv += __shfl_xor(lv, 32);

    // 2-way grp merge through LDS (aliases K buffers)
    float* Om = (float*)smem;          // [64 q][132] fp32 = 33.8 KB
    float* Lm = Om + 64 * 132;         // [64]
    if (grp == 1) {
#pragma unroll
        for (int ct = 0; ct < 8; ++ct)
#pragma unroll
            for (int r = 0; r < 4; ++r)
                Om[(wq * 16 + quad * 4 + r) * 132 + ct * 16 + n16] = o[ct][r];
        if (lane < 16) Lm[wq * 16 + n16] = lv;
    }
    __syncthreads();
    if (grp == 0) {
        float lsum[4];
#pragma unroll
        for (int r = 0; r < 4; ++r)
            lsum[r] = __shfl(lv, quad * 4 + r) + Lm[wq * 16 + quad * 4 + r];
#pragma unroll
        for (int ct = 0; ct < 8; ++ct) {
#pragma unroll
            for (int r = 0; r < 4; ++r) {
                int q = q0 + wq * 16 + quad * 4 + r;
                float ov = o[ct][r] + Om[(wq * 16 + quad * 4 + r) * 132 + ct * 16 + n16];
                out[((size_t)b * N + q) * Fc + ct * 16 + n16] = ov / lsum[r];
            }
        }
    }
}

extern "C" void kernel_launch(void* const* d_in, const int* in_sizes, int n_in,
                              void* d_out, int out_size, void* d_ws, size_t ws_size,
                              hipStream_t stream) {
    (void)in_sizes; (void)n_in; (void)out_size; (void)ws_size;
    const float* q_in  = (const float*)d_in[0];
    const float* kv_in = (const float*)d_in[1];
    const float* Wq = (const float*)d_in[2];
    const float* bq = (const float*)d_in[3];
    const float* Wk = (const float*)d_in[4];
    const float* bk = (const float*)d_in[5];
    const float* Wv = (const float*)d_in[6];
    const float* bv = (const float*)d_in[7];

    const size_t qkv = (size_t)BATCH * N * Fc;   // 2,097,152 elements
    u16* Qw  = (u16*)d_ws;              // bf16 [b][m][f], pre-scaled
    u16* Kw  = Qw + qkv;                // bf16 [b][m][f]
    u16* Vtw = Kw + qkv;                // bf16 [b][f][m]
    u16* WtG = Vtw + qkv;               // bf16 [3][f][c]  (total ws 12.68 MB)

    wtrans_kernel<<<dim3(3), dim3(256), 0, stream>>>(Wq, Wk, Wv, WtG);
    proj_kernel<<<dim3(64, 3, BATCH), dim3(256), 0, stream>>>(
        q_in, kv_in, WtG, bq, bk, bv, Qw, Kw, Vtw);
    attn_kernel<<<dim3(64, BATCH), dim3(512), 0, stream>>>(
        Qw, Kw, Vtw, (float*)d_out);
}

// Round 10
// 139.141 us; speedup vs baseline: 1.1837x; 1.0610x over previous
//
#include <hip/hip_runtime.h>
#include <stdint.h>

typedef unsigned short u16;
typedef __bf16 bf16x8 __attribute__((ext_vector_type(8)));
typedef unsigned short u16x8 __attribute__((ext_vector_type(8)));
typedef unsigned short u16x4 __attribute__((ext_vector_type(4)));
typedef float f32x4 __attribute__((ext_vector_type(4)));
typedef float f32x16 __attribute__((ext_vector_type(16)));

#define MFMA16(a, b, c) __builtin_amdgcn_mfma_f32_16x16x32_bf16((a), (b), (c), 0, 0, 0)
#define MFMA32(a, b, c) __builtin_amdgcn_mfma_f32_32x32x16_bf16((a), (b), (c), 0, 0, 0)

__device__ __forceinline__ u16 f2b(float f) {
    union { unsigned int i; float f; } v; v.f = f;
    unsigned int r = (v.i + 0x7FFFu + ((v.i >> 16) & 1u)) >> 16;
    return (u16)r;
}

constexpr int N = 4096;
constexpr int Cc = 128;
constexpr int Fc = 128;
constexpr int BATCH = 4;

constexpr int XS_STRIDE = 136;
constexpr int WT_STRIDE = 136;
constexpr int KS_STRIDE = 136;   // K tile [key128][c]
constexpr int VTS_STRIDE = 136;  // V tile [ch][key128]
constexpr int PS2_STRIDE = 40;   // per-wave P [32 q][32 key + pad] (80B rows)

// ---------------------------------------------------------------------------
// W pre-transpose: Wt[which][f][c] (bf16). grid 3 x 256.
// ---------------------------------------------------------------------------
__global__ __launch_bounds__(256) void wtrans_kernel(
    const float* __restrict__ Wq, const float* __restrict__ Wk,
    const float* __restrict__ Wv, u16* __restrict__ WtG)
{
    __shared__ __align__(16) u16 Wl[128 * 132];  // [c][f]
    const int tid = threadIdx.x;
    const int which = blockIdx.x;
    const float* W = which == 0 ? Wq : (which == 1 ? Wk : Wv);
#pragma unroll
    for (int it = 0; it < 16; ++it) {
        int idx4 = tid + it * 256; int e0 = idx4 * 4;
        int c = e0 >> 7, f = e0 & 127;
        float4 wv = *(const float4*)(W + e0);
        u16x4 h; h[0] = f2b(wv.x); h[1] = f2b(wv.y); h[2] = f2b(wv.z); h[3] = f2b(wv.w);
        *(u16x4*)&Wl[c * 132 + f] = h;
    }
    __syncthreads();
    u16* out = WtG + which * 16384;
#pragma unroll
    for (int it = 0; it < 8; ++it) {
        int idx8 = tid + it * 256; int e0 = idx8 * 8;
        int f = e0 >> 7, c = e0 & 127;
        u16x8 h;
#pragma unroll
        for (int j = 0; j < 8; ++j) h[j] = Wl[(c + j) * 132 + f];
        *(u16x8*)(out + e0) = h;
    }
}

// ---------------------------------------------------------------------------
// Projection (fp32 X, bf16 Wt -> bf16 workspace). grid (64,3,4) x 256.
// ---------------------------------------------------------------------------
__global__ __launch_bounds__(256) void proj_kernel(
    const float* __restrict__ q_in, const float* __restrict__ kv_in,
    const u16* __restrict__ WtG,
    const float* __restrict__ bq, const float* __restrict__ bk,
    const float* __restrict__ bv,
    u16* __restrict__ Qw, u16* __restrict__ Kw, u16* __restrict__ Vtw)
{
    __shared__ __align__(16) u16 Xs[64 * XS_STRIDE];   // [m][c] bf16
    __shared__ __align__(16) u16 Wt[128 * WT_STRIDE];  // [f][c] bf16

    const int tid = threadIdx.x;
    const int which = blockIdx.y;
    const int b = blockIdx.z;
    const int m0 = blockIdx.x * 64;

    const float* X = (which == 0 ? q_in : kv_in) + ((size_t)b * N + m0) * Cc;
    const u16* Wsrc = WtG + which * 16384;
    const float* bias = which == 0 ? bq : (which == 1 ? bk : bv);

#pragma unroll
    for (int it = 0; it < 8; ++it) {
        int idx4 = tid + it * 256; int e0 = idx4 * 4;
        int r = e0 >> 7, c = e0 & 127;
        float4 xv = *(const float4*)(X + e0);
        u16x4 h; h[0] = f2b(xv.x); h[1] = f2b(xv.y); h[2] = f2b(xv.z); h[3] = f2b(xv.w);
        *(u16x4*)&Xs[r * XS_STRIDE + c] = h;
    }
#pragma unroll
    for (int it = 0; it < 8; ++it) {
        int idx8 = tid + it * 256; int e0 = idx8 * 8;
        int f = e0 >> 7, c = e0 & 127;
        *(u16x8*)&Wt[f * WT_STRIDE + c] = *(const u16x8*)(Wsrc + e0);
    }
    __syncthreads();

    const int lane = tid & 63;
    const int w = tid >> 6;
    const int n16 = lane & 15;
    const int quad = lane >> 4;

    if (which < 2) {
        bf16x8 ax[4];
#pragma unroll
        for (int kk = 0; kk < 4; ++kk)
            ax[kk] = *(const bf16x8*)&Xs[(w * 16 + n16) * XS_STRIDE + kk * 32 + quad * 8];
        const float scale = (which == 0) ? 0.08838834764831845f : 1.0f;
        u16* Out = (which == 0) ? Qw : Kw;
#pragma unroll
        for (int ft = 0; ft < 8; ++ft) {
            f32x4 acc = {0.f, 0.f, 0.f, 0.f};
#pragma unroll
            for (int kk = 0; kk < 4; ++kk) {
                bf16x8 bw = *(const bf16x8*)&Wt[(ft * 16 + n16) * WT_STRIDE + kk * 32 + quad * 8];
                acc = MFMA16(ax[kk], bw, acc);
            }
            float bias_f = bias[ft * 16 + n16];
#pragma unroll
            for (int r = 0; r < 4; ++r) {
                int row = m0 + w * 16 + quad * 4 + r;
                Out[((size_t)b * N + row) * Fc + ft * 16 + n16] = f2b((acc[r] + bias_f) * scale);
            }
        }
    } else {
#pragma unroll
        for (int ft2 = 0; ft2 < 2; ++ft2) {
            int ftg = w * 2 + ft2;
            bf16x8 aw[4];
#pragma unroll
            for (int kk = 0; kk < 4; ++kk)
                aw[kk] = *(const bf16x8*)&Wt[(ftg * 16 + n16) * WT_STRIDE + kk * 32 + quad * 8];
            float bias4[4];
#pragma unroll
            for (int r = 0; r < 4; ++r) bias4[r] = bias[ftg * 16 + quad * 4 + r];
#pragma unroll
            for (int nt = 0; nt < 4; ++nt) {
                f32x4 acc = {0.f, 0.f, 0.f, 0.f};
#pragma unroll
                for (int kk = 0; kk < 4; ++kk) {
                    bf16x8 bx = *(const bf16x8*)&Xs[(nt * 16 + n16) * XS_STRIDE + kk * 32 + quad * 8];
                    acc = MFMA16(aw[kk], bx, acc);
                }
#pragma unroll
                for (int r = 0; r < 4; ++r) {
                    int fg = ftg * 16 + quad * 4 + r;
                    int rowg = m0 + nt * 16 + n16;
                    Vtw[((size_t)b * Fc + fg) * N + rowg] = f2b(acc[r] + bias4[r]);
                }
            }
        }
    }
}

// ---------------------------------------------------------------------------
// Flash attention, 32x32x16 MFMA (statically-scaled softmax, deferred l).
// 512 threads = 8 waves = 2 qg (32 q-rows) x 4 grp (32-key quarters of a
// 128-key tile); 64 q-rows/block; dbuf K/V LDS, ONE barrier per tile.
// Per wave per tile: S = 8-MFMA chain (ak 8 b128), PV = 8 MFMA (bv 8 b128),
// P via wave-private LDS (4 b64 + 2 b128).  LDS ops/CU/tile ~240 vs r9's 368.
// 32x32 layouts: A/B m|n = lane&31, k = 8*(lane>>5)+j;
// C/D col = lane&31, row = (reg&3)+8*(reg>>2)+4*(lane>>5)  [m74/m101].
// S^T (A=K,B=Q): col=q -> each lane's 16 S-values share one q (l-reduce = 1 shfl).
// grid (64 q-tiles, 4 batches), 512 threads, LDS 156 KB (1 block/CU).
// ---------------------------------------------------------------------------
__global__ __launch_bounds__(512, 2) void attn_kernel(
    const u16* __restrict__ Qw, const u16* __restrict__ Kw,
    const u16* __restrict__ Vtw, float* __restrict__ out)
{
    // [Kbuf0 | Kbuf1 | Vbuf0 | Vbuf1 | P]  (u16 elements) = 159744 B
    __shared__ __align__(16) u16 smem[2 * 128 * KS_STRIDE + 2 * 128 * VTS_STRIDE + 8 * 32 * PS2_STRIDE];
    u16* Kbuf = smem;
    u16* Vbuf = smem + 2 * 128 * KS_STRIDE;
    u16* Ps   = Vbuf + 2 * 128 * VTS_STRIDE;

    const int tid = threadIdx.x;
    const int b = blockIdx.y;
    const int q0 = blockIdx.x * 64;
    const int lane = tid & 63;
    const int w = tid >> 6;      // 0..7
    const int grp = w & 3;       // 32-key quarter of the 128-key tile
    const int qg = w >> 2;       // q group (32 of the block's 64 rows)
    const int l31 = lane & 31;
    const int l5 = lane >> 5;

    // Q B-fragments (n = q = l31), 8 k-steps of 16, held for the whole loop
    bf16x8 aq[8];
    {
        const u16* qrow = Qw + ((size_t)b * N + q0 + qg * 32 + l31) * Cc;
#pragma unroll
        for (int k = 0; k < 8; ++k)
            aq[k] = *(const bf16x8*)(qrow + k * 16 + 8 * l5);
    }

    // staging maps: 512 threads stage 128x128 K and 128x128 Vt per tile
    int rr[4], cc[4];
#pragma unroll
    for (int it = 0; it < 4; ++it) {
        int idx8 = tid + it * 512; int e0 = idx8 * 8;
        rr[it] = e0 >> 7; cc[it] = e0 & 127;
    }
    const u16* Kbase = Kw + (size_t)b * N * Cc;
    const u16* Vbase = Vtw + (size_t)b * Fc * N;

    // prologue: prefetch tile 0
    u16x8 kreg[4], vreg[4];
#pragma unroll
    for (int it = 0; it < 4; ++it) {
        kreg[it] = *(const u16x8*)(Kbase + (size_t)rr[it] * Cc + cc[it]);
        vreg[it] = *(const u16x8*)(Vbase + (size_t)rr[it] * N + cc[it]);
    }

    f32x16 o[4];
#pragma unroll
    for (int ct = 0; ct < 4; ++ct)
#pragma unroll
        for (int e = 0; e < 16; ++e) o[ct][e] = 0.f;
    float lloc = 0.f;

    u16* Psw = Ps + w * 32 * PS2_STRIDE;  // wave-private [32 q][32 key]

    for (int t = 0; t < N / 128; ++t) {
        u16* Ks  = Kbuf + (t & 1) * 128 * KS_STRIDE;
        u16* Vts = Vbuf + (t & 1) * 128 * VTS_STRIDE;

        // commit prefetched tile (vmcnt drains here)
#pragma unroll
        for (int it = 0; it < 4; ++it) {
            *(u16x8*)&Ks[rr[it] * KS_STRIDE + cc[it]] = kreg[it];
            *(u16x8*)&Vts[rr[it] * VTS_STRIDE + cc[it]] = vreg[it];
        }
        __syncthreads();   // single barrier per tile

        if (t + 1 < N / 128) {
            int k0n = (t + 1) * 128;
#pragma unroll
            for (int it = 0; it < 4; ++it) {
                kreg[it] = *(const u16x8*)(Kbase + (size_t)(k0n + rr[it]) * Cc + cc[it]);
                vreg[it] = *(const u16x8*)(Vbase + (size_t)rr[it] * N + k0n + cc[it]);
            }
        }

        // S^T = K Q^T over this wave's 32 keys x 32 q: one 32x32 acc chain.
        // D: col = q = l31, row = key = (reg&3)+8*(reg>>2)+4*l5.
        f32x16 st;
#pragma unroll
        for (int e = 0; e < 16; ++e) st[e] = 0.f;
#pragma unroll
        for (int k = 0; k < 8; ++k) {
            bf16x8 ak = *(const bf16x8*)&Ks[(grp * 32 + l31) * KS_STRIDE + k * 16 + 8 * l5];
            st = MFMA32(ak, aq[k], st);
        }

        // p = exp(s); per-lane l partial (all 16 values share q = l31);
        // reg-quad rq holds 4 consecutive keys at base 8*rq + 4*l5 -> b64 store
#pragma unroll
        for (int rq = 0; rq < 4; ++rq) {
            float e0 = __expf(st[4 * rq + 0]), e1 = __expf(st[4 * rq + 1]);
            float e2 = __expf(st[4 * rq + 2]), e3 = __expf(st[4 * rq + 3]);
            lloc += (e0 + e1) + (e2 + e3);
            u16x4 pk; pk[0] = f2b(e0); pk[1] = f2b(e1); pk[2] = f2b(e2); pk[3] = f2b(e3);
            *(u16x4*)&Psw[l31 * PS2_STRIDE + 8 * rq + 4 * l5] = pk;
        }

        // O += P V: A = P[q32][key16/step] (m = q = l31, k = 8*l5+j),
        //           B = Vts[ch][key] (n = ch = l31, k = key). 2 ksteps x 4 ch-tiles.
#pragma unroll
        for (int ks = 0; ks < 2; ++ks) {
            bf16x8 pa = *(const bf16x8*)&Psw[l31 * PS2_STRIDE + ks * 16 + 8 * l5];
#pragma unroll
            for (int ct = 0; ct < 4; ++ct) {
                bf16x8 bv_ = *(const bf16x8*)&Vts[(ct * 32 + l31) * VTS_STRIDE + grp * 32 + ks * 16 + 8 * l5];
                o[ct] = MFMA32(pa, bv_, o[ct]);
            }
        }
        // no trailing barrier: next tile commits into the other buffer
    }
    __syncthreads();   // protect merge-phase aliasing of the tile buffers

    // l: lanes l and l+32 hold the two key-halves of q = qg*32+l31
    float lv = lloc;
    lv += __shfl_xor(lv, 32);

    // 4-way grp merge through LDS (aliases K/V buffers)
    float* Om = (float*)smem;            // [3*64 rows][132] fp32 = 101.4 KB
    float* Lm = Om + 3 * 64 * 132;       // [3*64]
    if (grp != 0) {
        int qb = (grp - 1) * 64 + qg * 32;
#pragma unroll
        for (int ct = 0; ct < 4; ++ct)
#pragma unroll
            for (int reg = 0; reg < 16; ++reg) {
                int qr = (reg & 3) + 8 * (reg >> 2) + 4 * l5;
                Om[(qb + qr) * 132 + ct * 32 + l31] = o[ct][reg];
            }
        if (lane < 32) Lm[(grp - 1) * 64 + qg * 32 + l31] = lv;
    }
    __syncthreads();
    if (grp == 0) {
#pragma unroll
        for (int reg = 0; reg < 16; ++reg) {
            int qr = (reg & 3) + 8 * (reg >> 2) + 4 * l5;   // 0..31 within qg
            float ls = __shfl(lv, qr);                       // l for q=qg*32+qr
#pragma unroll
            for (int j = 0; j < 3; ++j)
                ls += Lm[j * 64 + qg * 32 + qr];
            int q = q0 + qg * 32 + qr;
#pragma unroll
            for (int ct = 0; ct < 4; ++ct) {
                float ov = o[ct][reg];
#pragma unroll
                for (int j = 0; j < 3; ++j)
                    ov += Om[(j * 64 + qg * 32 + qr) * 132 + ct * 32 + l31];
                out[((size_t)b * N + q) * Fc + ct * 32 + l31] = ov / ls;
            }
        }
    }
}

extern "C" void kernel_launch(void* const* d_in, const int* in_sizes, int n_in,
                              void* d_out, int out_size, void* d_ws, size_t ws_size,
                              hipStream_t stream) {
    (void)in_sizes; (void)n_in; (void)out_size; (void)ws_size;
    const float* q_in  = (const float*)d_in[0];
    const float* kv_in = (const float*)d_in[1];
    const float* Wq = (const float*)d_in[2];
    const float* bq = (const float*)d_in[3];
    const float* Wk = (const float*)d_in[4];
    const float* bk = (const float*)d_in[5];
    const float* Wv = (const float*)d_in[6];
    const float* bv = (const float*)d_in[7];

    const size_t qkv = (size_t)BATCH * N * Fc;   // 2,097,152 elements
    u16* Qw  = (u16*)d_ws;              // bf16 [b][m][f], pre-scaled
    u16* Kw  = Qw + qkv;                // bf16 [b][m][f]
    u16* Vtw = Kw + qkv;                // bf16 [b][f][m]
    u16* WtG = Vtw + qkv;               // bf16 [3][f][c]  (total ws 12.68 MB)

    wtrans_kernel<<<dim3(3), dim3(256), 0, stream>>>(Wq, Wk, Wv, WtG);
    proj_kernel<<<dim3(64, 3, BATCH), dim3(256), 0, stream>>>(
        q_in, kv_in, WtG, bq, bk, bv, Qw, Kw, Vtw);
    attn_kernel<<<dim3(64, BATCH), dim3(512), 0, stream>>>(
        Qw, Kw, Vtw, (float*)d_out);
}